// Round 5
// baseline (744.135 us; speedup 1.0000x reference)
//
#include <hip/hip_runtime.h>
#include <math.h>

#define NK 6
#define NB 8
#define NT 12
#define D 256      // DIM == HALF == 256
#define DP (D+4)   // padded LDS row
#define NG 8       // offset groups == sampling points
#define NHD 8      // num heads
#define HW 256     // HBEV == WBEV
#define NQ (NK*NB*NT)   // 576 queries
#define NBLK (NQ/2)     // 288 blocks, 2 queries each

// R5: 2-query pairing. Each block processes queries (2b, 2b+1) (same bev
// image). Every weight element is loaded once from L2 and used twice
// (q0/q1 accumulators in the same thread) -> L2 weight traffic halves
// (1.15 GB -> 0.58 GB per dispatch). LDS trimmed to ~79.5 KB so 2 blocks
// stay resident per CU: kse->tmpk->wsamp share one buffer (in-place relu
// is barrier-separated), h1 doubles as tmp1, qse doubles as oatt, psum
// replaced by a 2-lane shuffle reduction.
__global__ __launch_bounds__(256)
void dca_pair(const float* __restrict__ dec_embed,
              const float* __restrict__ bev_feat,
              const float* __restrict__ query_scale,
              const float* __restrict__ ref_points,
              const float* __restrict__ Wq,     const float* __restrict__ bq,
              const float* __restrict__ Wk,     const float* __restrict__ Wv,
              const float* __restrict__ pq_W1,  const float* __restrict__ pq_b1,
              const float* __restrict__ pq_W2,  const float* __restrict__ pq_b2,
              const float* __restrict__ pk_W1,  const float* __restrict__ pk_b1,
              const float* __restrict__ pk_W2,  const float* __restrict__ pk_b2,
              const float* __restrict__ off_W1, const float* __restrict__ off_b1,
              const float* __restrict__ off_W2, const float* __restrict__ off_b2,
              const float* __restrict__ out_W,  const float* __restrict__ out_b,
              float* __restrict__ out)
{
    __shared__ float de[2][D];          // 2 KB
    __shared__ float conq[2][D];        // 2 KB
    __shared__ float qse[2][D];         // 2 KB  (reused as oatt after st.7)
    __shared__ float posq[2][D];        // 2 KB
    __shared__ float h1buf[2][NG*64];   // 4 KB  h1 (st3-4); tmp1[2][D] (st7-7.5)
    __shared__ float gxy[2][NG][2];
    __shared__ float sim[2][NHD][NG];
    __shared__ float samp[2][NG][DP];   // 16.25 KB  sampled bev rows
    __shared__ float kst [2][NG][DP];   // 16.25 KB  kse -> tmpk -> wsamp
    __shared__ float wqk [2][NHD][DP];  // 16.25 KB  Wk  contracted with conq
    __shared__ float wqpk[2][NHD][DP];  // 16.25 KB  pk_W2 contracted with posq
    // total ~79.5 KB -> 2 blocks/CU

    const int tid = threadIdx.x;
    const int q0  = blockIdx.x * 2;
    const int bb  = (q0 / NT) % NB;      // same for q0 and q0+1 (NT even)

    const float NORM = 0.01953125f;          // 2/102.4
    const float TWO_PI = 6.28318530717958647692f;
    const float L2_40_OVER_64 = 5.32192809488736234787f / 64.0f;  // log2(40)/64

    // ---- stage 1: load both dec_embed rows ----
    de[0][tid] = dec_embed[(size_t)q0 * D + tid];
    de[1][tid] = dec_embed[(size_t)(q0 + 1) * D + tid];
    __syncthreads();

    // ---- stage 2: con_q = de @ Wq + bq (paired) ; qse sine embeds ----
    {
        float a0 = bq[tid], a1 = a0;
        #pragma unroll 4
        for (int i = 0; i < D; i += 4) {
            float w0 = Wq[(i + 0) * D + tid], w1 = Wq[(i + 1) * D + tid];
            float w2 = Wq[(i + 2) * D + tid], w3 = Wq[(i + 3) * D + tid];
            float4 d0 = *(const float4*)&de[0][i];
            float4 d1 = *(const float4*)&de[1][i];
            a0 += d0.x * w0 + d0.y * w1 + d0.z * w2 + d0.w * w3;
            a1 += d1.x * w0 + d1.y * w1 + d1.z * w2 + d1.w * w3;
        }
        conq[0][tid] = a0;
        conq[1][tid] = a1;
        int m = (tid & 127) >> 1;
        float freq = TWO_PI / exp2f((float)m * L2_40_OVER_64);
        #pragma unroll
        for (int p = 0; p < 2; ++p) {
            float rx = ref_points[(size_t)(q0 + p) * 2 + 0] * NORM;
            float ry = ref_points[(size_t)(q0 + p) * 2 + 1] * NORM;
            float pos = (tid < 128) ? ry : rx;
            float e = pos * freq;
            qse[p][tid] = (tid & 1) ? __cosf(e) : __sinf(e);
        }
    }
    __syncthreads();

    // ---- stage 3: offset MLP layer 1 (32 -> 64, exact GELU, paired) ----
    for (int idx = tid; idx < NG * 64; idx += 256) {
        int g = idx >> 6, j = idx & 63;
        float a0 = off_b1[j], a1 = a0;
        #pragma unroll
        for (int i = 0; i < 32; i += 4) {
            float w0 = off_W1[(i + 0) * 64 + j], w1 = off_W1[(i + 1) * 64 + j];
            float w2 = off_W1[(i + 2) * 64 + j], w3 = off_W1[(i + 3) * 64 + j];
            float4 c0 = *(const float4*)&conq[0][g * 32 + i];
            float4 c1 = *(const float4*)&conq[1][g * 32 + i];
            a0 += c0.x * w0 + c0.y * w1 + c0.z * w2 + c0.w * w3;
            a1 += c1.x * w0 + c1.y * w1 + c1.z * w2 + c1.w * w3;
        }
        h1buf[0][idx] = 0.5f * a0 * (1.0f + erff(a0 * 0.70710678118654752440f));
        h1buf[1][idx] = 0.5f * a1 * (1.0f + erff(a1 * 0.70710678118654752440f));
    }
    __syncthreads();

    // ---- stage 4: offset MLP layer 2 (64 -> 2), tanh*4, add ref, normalize ----
    if (tid < NG * 2) {
        int g = tid >> 1, c = tid & 1;
        float a0 = off_b2[c], a1 = a0;
        #pragma unroll
        for (int j = 0; j < 64; j += 4) {
            float w0 = off_W2[(j + 0) * 2 + c], w1 = off_W2[(j + 1) * 2 + c];
            float w2 = off_W2[(j + 2) * 2 + c], w3 = off_W2[(j + 3) * 2 + c];
            float4 h0 = *(const float4*)&h1buf[0][g * 64 + j];
            float4 h14 = *(const float4*)&h1buf[1][g * 64 + j];
            a0 += h0.x * w0 + h0.y * w1 + h0.z * w2 + h0.w * w3;
            a1 += h14.x * w0 + h14.y * w1 + h14.z * w2 + h14.w * w3;
        }
        gxy[0][g][c] = (ref_points[(size_t)q0 * 2 + c] + tanhf(a0) * 4.0f) * NORM;
        gxy[1][g][c] = (ref_points[(size_t)(q0 + 1) * 2 + c] + tanhf(a1) * 4.0f) * NORM;
    }
    __syncthreads();

    // ---- stage 5: per-query gather (loads first, kse hides latency), then
    //      paired wqk contraction ----
    {
        const float* ch = bev_feat + ((size_t)bb * D + tid) * (HW * HW);
        int m = (tid & 127) >> 1;
        float freq = TWO_PI / exp2f((float)m * L2_40_OVER_64);
        #pragma unroll 1
        for (int p = 0; p < 2; ++p) {
            float v00[NG], v01[NG], v10[NG], v11[NG], wxA[NG], wyA[NG];
            #pragma unroll
            for (int g = 0; g < NG; ++g) {
                float gx = gxy[p][g][0], gy = gxy[p][g][1];
                float ix = ((gx + 1.0f) * HW - 1.0f) * 0.5f;
                float iy = ((gy + 1.0f) * HW - 1.0f) * 0.5f;
                float fx0 = floorf(ix), fy0 = floorf(iy);
                wxA[g] = ix - fx0; wyA[g] = iy - fy0;
                int x0 = (int)fx0, y0 = (int)fy0;
                bool xin0 = (x0 >= 0) && (x0 < HW);
                bool xin1 = (x0 + 1 >= 0) && (x0 + 1 < HW);
                bool yin0 = (y0 >= 0) && (y0 < HW);
                bool yin1 = (y0 + 1 >= 0) && (y0 + 1 < HW);
                v00[g] = (yin0 && xin0) ? ch[y0 * HW + x0]           : 0.f;
                v01[g] = (yin0 && xin1) ? ch[y0 * HW + x0 + 1]       : 0.f;
                v10[g] = (yin1 && xin0) ? ch[(y0 + 1) * HW + x0]     : 0.f;
                v11[g] = (yin1 && xin1) ? ch[(y0 + 1) * HW + x0 + 1] : 0.f;
            }
            // kse (pure VALU) overlaps the in-flight gathers
            #pragma unroll
            for (int g = 0; g < NG; ++g) {
                float pos = (tid < 128) ? gxy[p][g][1] : gxy[p][g][0];
                float e = pos * freq;
                kst[p][g][tid] = (tid & 1) ? __cosf(e) : __sinf(e);
            }
            #pragma unroll
            for (int g = 0; g < NG; ++g) {
                float wx = wxA[g], wy = wyA[g];
                samp[p][g][tid] = v00[g] * (1.f - wx) * (1.f - wy) + v01[g] * wx * (1.f - wy)
                                + v10[g] * (1.f - wx) * wy         + v11[g] * wx * wy;
            }
        }
        // wqk[p][h][tid] = sum_d Wk[tid][h*32+d] * conq[p][h*32+d] (shared row loads)
        {
            float ak[2][NHD] = {{0.f}};
            const float* wkrow = Wk + (size_t)tid * D;
            #pragma unroll
            for (int c = 0; c < D; c += 4) {
                float4 w  = *(const float4*)&wkrow[c];
                float4 c0 = *(const float4*)&conq[0][c];
                float4 c1 = *(const float4*)&conq[1][c];
                ak[0][c >> 5] += w.x * c0.x + w.y * c0.y + w.z * c0.z + w.w * c0.w;
                ak[1][c >> 5] += w.x * c1.x + w.y * c1.y + w.z * c1.z + w.w * c1.w;
            }
            #pragma unroll
            for (int h = 0; h < NHD; ++h) {
                wqk[0][h][tid] = ak[0][h];
                wqk[1][h][tid] = ak[1][h];
            }
        }
    }
    __syncthreads();

    // ---- stage 7: tmpk = relu(kse @ pk_W1 + b1) in-place, + pos-q layer1 ----
    {
        float acc[2][NG + 1];
        float bk = pk_b1[tid], bqv = pq_b1[tid];
        #pragma unroll
        for (int p = 0; p < 2; ++p) {
            #pragma unroll
            for (int g = 0; g < NG; ++g) acc[p][g] = bk;
            acc[p][NG] = bqv;
        }
        #pragma unroll 2
        for (int i = 0; i < D; i += 4) {
            float k0 = pk_W1[(i + 0) * D + tid], k1 = pk_W1[(i + 1) * D + tid];
            float k2 = pk_W1[(i + 2) * D + tid], k3 = pk_W1[(i + 3) * D + tid];
            float u0 = pq_W1[(i + 0) * D + tid], u1 = pq_W1[(i + 1) * D + tid];
            float u2 = pq_W1[(i + 2) * D + tid], u3 = pq_W1[(i + 3) * D + tid];
            #pragma unroll
            for (int p = 0; p < 2; ++p) {
                #pragma unroll
                for (int g = 0; g < NG; ++g) {
                    float4 s = *(const float4*)&kst[p][g][i];
                    acc[p][g] += s.x * k0 + s.y * k1 + s.z * k2 + s.w * k3;
                }
                float4 t = *(const float4*)&qse[p][i];
                acc[p][NG] += t.x * u0 + t.y * u1 + t.z * u2 + t.w * u3;
            }
        }
        __syncthreads();   // ALL kse reads complete before in-place overwrite
        #pragma unroll
        for (int p = 0; p < 2; ++p) {
            #pragma unroll
            for (int g = 0; g < NG; ++g) kst[p][g][tid] = fmaxf(acc[p][g], 0.f);
            h1buf[p][tid] = fmaxf(acc[p][NG], 0.f);   // tmp1
        }
    }
    __syncthreads();

    // ---- stage 7.5: posq = (tmp1 @ pq_W2 + b2) * query_scale (paired) ----
    {
        float a0 = pq_b2[tid], a1 = a0;
        #pragma unroll 4
        for (int i = 0; i < D; i += 4) {
            float w0 = pq_W2[(i + 0) * D + tid], w1 = pq_W2[(i + 1) * D + tid];
            float w2 = pq_W2[(i + 2) * D + tid], w3 = pq_W2[(i + 3) * D + tid];
            float4 t0 = *(const float4*)&h1buf[0][i];
            float4 t1 = *(const float4*)&h1buf[1][i];
            a0 += t0.x * w0 + t0.y * w1 + t0.z * w2 + t0.w * w3;
            a1 += t1.x * w0 + t1.y * w1 + t1.z * w2 + t1.w * w3;
        }
        posq[0][tid] = a0 * query_scale[(size_t)q0 * D + tid];
        posq[1][tid] = a1 * query_scale[(size_t)(q0 + 1) * D + tid];
    }
    __syncthreads();

    // ---- stage 8: wqpk[p][h][tid] = sum_d pk_W2[tid][h*32+d]*posq[p][h*32+d] ----
    // (pk_b2 contribution is g-independent -> softmax shift-invariant, dropped)
    {
        float aw[2][NHD] = {{0.f}};
        const float* wrow = pk_W2 + (size_t)tid * D;
        #pragma unroll
        for (int c = 0; c < D; c += 4) {
            float4 w  = *(const float4*)&wrow[c];
            float4 p0 = *(const float4*)&posq[0][c];
            float4 p1 = *(const float4*)&posq[1][c];
            aw[0][c >> 5] += w.x * p0.x + w.y * p0.y + w.z * p0.z + w.w * p0.w;
            aw[1][c >> 5] += w.x * p1.x + w.y * p1.y + w.z * p1.z + w.w * p1.w;
        }
        #pragma unroll
        for (int h = 0; h < NHD; ++h) {
            wqpk[0][h][tid] = aw[0][h];
            wqpk[1][h][tid] = aw[1][h];
        }
    }
    __syncthreads();

    // ---- stage 9: sim[p][h][g] = SCALE*(samp.wqk + tmpk.wqpk), shfl-reduced ----
    {
        int p = tid >> 7;
        int rem = tid & 127;
        int h = rem >> 4;
        int g = (rem >> 1) & 7;
        int i0 = (tid & 1) * 128;
        float s = 0.f;
        #pragma unroll
        for (int i = i0; i < i0 + 128; i += 4) {
            float4 a = *(const float4*)&samp[p][g][i];
            float4 b = *(const float4*)&wqk[p][h][i];
            float4 c = *(const float4*)&kst[p][g][i];
            float4 d = *(const float4*)&wqpk[p][h][i];
            s += a.x * b.x + a.y * b.y + a.z * b.z + a.w * b.w;
            s += c.x * d.x + c.y * d.y + c.z * d.z + c.w * d.w;
        }
        s += __shfl_down(s, 1, 64);
        if (!(tid & 1)) sim[p][h][g] = s * 0.125f;   // SCALE = 64^-0.5
    }
    __syncthreads();

    // ---- stage 10: softmax over g ----
    if (tid < 2 * NHD) {
        int p = tid >> 3, h = tid & 7;
        float mx = sim[p][h][0];
        for (int g = 1; g < NG; ++g) mx = fmaxf(mx, sim[p][h][g]);
        float ex[NG], sum = 0.f;
        #pragma unroll
        for (int g = 0; g < NG; ++g) { ex[g] = __expf(sim[p][h][g] - mx); sum += ex[g]; }
        float inv = 1.0f / sum;
        #pragma unroll
        for (int g = 0; g < NG; ++g) sim[p][h][g] = ex[g] * inv;
    }
    __syncthreads();

    // ---- stage 11: wsamp[p][h][i] = sum_g attn[p][h][g]*samp[p][g][i] (into kst) ----
    {
        #pragma unroll
        for (int p = 0; p < 2; ++p) {
            float wsm[NHD];
            #pragma unroll
            for (int h = 0; h < NHD; ++h) wsm[h] = 0.f;
            #pragma unroll
            for (int g = 0; g < NG; ++g) {
                float sv = samp[p][g][tid];
                #pragma unroll
                for (int h = 0; h < NHD; ++h) wsm[h] += sim[p][h][g] * sv;
            }
            #pragma unroll
            for (int h = 0; h < NHD; ++h) kst[p][h][tid] = wsm[h];
        }
    }
    __syncthreads();

    // ---- stage 12: oatt[p][c] = wsamp[p][c>>5] . Wv[:,c] (into qse) ----
    {
        int h = tid >> 5;
        float a0 = 0.f, a1 = 0.f;
        #pragma unroll 4
        for (int i = 0; i < D; i += 4) {
            float w0 = Wv[(i + 0) * D + tid], w1 = Wv[(i + 1) * D + tid];
            float w2 = Wv[(i + 2) * D + tid], w3 = Wv[(i + 3) * D + tid];
            float4 k0 = *(const float4*)&kst[0][h][i];
            float4 k1 = *(const float4*)&kst[1][h][i];
            a0 += k0.x * w0 + k0.y * w1 + k0.z * w2 + k0.w * w3;
            a1 += k1.x * w0 + k1.y * w1 + k1.z * w2 + k1.w * w3;
        }
        qse[0][tid] = a0;   // oatt
        qse[1][tid] = a1;
    }
    __syncthreads();

    // ---- stage 13: out = oatt @ out_W + out_b + dec_embed (paired) ----
    {
        float b = out_b[tid];
        float a0 = b, a1 = b;
        #pragma unroll 4
        for (int i = 0; i < D; i += 4) {
            float w0 = out_W[(i + 0) * D + tid], w1 = out_W[(i + 1) * D + tid];
            float w2 = out_W[(i + 2) * D + tid], w3 = out_W[(i + 3) * D + tid];
            float4 o0 = *(const float4*)&qse[0][i];
            float4 o1 = *(const float4*)&qse[1][i];
            a0 += o0.x * w0 + o0.y * w1 + o0.z * w2 + o0.w * w3;
            a1 += o1.x * w0 + o1.y * w1 + o1.z * w2 + o1.w * w3;
        }
        out[(size_t)q0 * D + tid]       = a0 + de[0][tid];
        out[(size_t)(q0 + 1) * D + tid] = a1 + de[1][tid];
    }
}

extern "C" void kernel_launch(void* const* d_in, const int* in_sizes, int n_in,
                              void* d_out, int out_size, void* d_ws, size_t ws_size,
                              hipStream_t stream) {
    const float* dec_embed   = (const float*)d_in[0];
    const float* bev_feat    = (const float*)d_in[1];
    const float* query_scale = (const float*)d_in[2];
    const float* ref_points  = (const float*)d_in[3];
    const float* Wq     = (const float*)d_in[4];
    const float* bq     = (const float*)d_in[5];
    const float* Wk     = (const float*)d_in[6];
    const float* Wv     = (const float*)d_in[7];
    const float* pq_W1  = (const float*)d_in[8];
    const float* pq_b1  = (const float*)d_in[9];
    const float* pq_W2  = (const float*)d_in[10];
    const float* pq_b2  = (const float*)d_in[11];
    const float* pk_W1  = (const float*)d_in[12];
    const float* pk_b1  = (const float*)d_in[13];
    const float* pk_W2  = (const float*)d_in[14];
    const float* pk_b2  = (const float*)d_in[15];
    const float* off_W1 = (const float*)d_in[16];
    const float* off_b1 = (const float*)d_in[17];
    const float* off_W2 = (const float*)d_in[18];
    const float* off_b2 = (const float*)d_in[19];
    const float* out_W  = (const float*)d_in[20];
    const float* out_b  = (const float*)d_in[21];
    float* out = (float*)d_out;

    dca_pair<<<NBLK, 256, 0, stream>>>(dec_embed, bev_feat, query_scale, ref_points,
                                       Wq, bq, Wk, Wv,
                                       pq_W1, pq_b1, pq_W2, pq_b2,
                                       pk_W1, pk_b1, pk_W2, pk_b2,
                                       off_W1, off_b1, off_W2, off_b2,
                                       out_W, out_b, out);
}